// Round 1
// 491.545 us; speedup vs baseline: 1.0653x; 1.0653x over previous
//
#include <hip/hip_runtime.h>

#define NN 100000
#define NE 1600000

typedef __attribute__((ext_vector_type(8))) short short8;   // 8 bf16 = 4 VGPRs (MFMA A/B frag)
typedef __attribute__((ext_vector_type(4))) float f32x4;    // MFMA C/D frag

// bf16 helpers
static __device__ __forceinline__ unsigned f2bf_rne(float f) {
    unsigned u = __float_as_uint(f);
    return (u + 0x7FFFu + ((u >> 16) & 1u)) >> 16;   // round-to-nearest-even
}
static __device__ __forceinline__ float bf_lo(unsigned u) { return __uint_as_float(u << 16); }
static __device__ __forceinline__ float bf_hi(unsigned u) { return __uint_as_float(u & 0xFFFF0000u); }

__global__ __launch_bounds__(256) void k_init(unsigned long long* packed, int n) {
    int i = blockIdx.x * 256 + threadIdx.x;
    if (i < n) packed[i] = 0ull;
}

// W [128k x 128n] fp32 -> W^T bf16 hi/lo pair, [n][k] row-major so MFMA B-frags
// (lane needs 8 consecutive k at fixed n) are one contiguous 16B load.
__global__ __launch_bounds__(256) void k_prep(const float* __restrict__ W,
                                              ushort* __restrict__ Wth,
                                              ushort* __restrict__ Wtl) {
    int idx = blockIdx.x * 256 + threadIdx.x;   // 0..16383
    int k = idx >> 7, n = idx & 127;
    float w = W[idx];
    unsigned hi = f2bf_rne(w);
    unsigned lo = f2bf_rne(w - bf_lo(hi));      // residual: W ~= hi + lo to ~2^-17 rel
    Wth[n * 128 + k] = (ushort)hi;
    Wtl[n * 128 + k] = (ushort)lo;
}

// ---------------- MFMA GEMM core: 32 rows x 128 cols per block, 4 waves ----------------
// Wave w owns cols [32w, 32w+32): 2x2 frags of 16x16, K-loop 4 steps of 32.
// A staged in LDS bf16 [32][136] (stride 272B = 17*16B: b128-aligned, ~2-way banks).
// B frags loaded straight from global (32KB bf16 W^T stays L1/L2-hot across 3125 blocks).
// SPLIT_A: fp32 A split hi/lo -> Ahi*Whi + Ahi*Wlo + Alo*Whi (~fp32-exact).
template <bool SPLIT_A>
static __device__ __forceinline__ void mfma_tile(const ushort* sAh, const ushort* sAl,
                                                 const ushort* __restrict__ Wth,
                                                 const ushort* __restrict__ Wtl,
                                                 unsigned* __restrict__ Cb,
                                                 size_t r0, int t) {
    int w  = t >> 6;
    int l  = t & 63;
    int lr = l & 15;            // row idx within A-frag / col idx within B-frag
    int lk = (l >> 4) << 3;     // k offset 0,8,16,24 within the 32-wide k-step
    int n0 = w * 32;

    short8 bh[2][4], bl[2][4];
#pragma unroll
    for (int cf = 0; cf < 2; ++cf)
#pragma unroll
        for (int ks = 0; ks < 4; ++ks) {
            int n = n0 + cf * 16 + lr;
            bh[cf][ks] = *(const short8*)&Wth[n * 128 + ks * 32 + lk];
            bl[cf][ks] = *(const short8*)&Wtl[n * 128 + ks * 32 + lk];
        }

    f32x4 zero = {0.f, 0.f, 0.f, 0.f};
    f32x4 acc[2][2] = {{zero, zero}, {zero, zero}};

    __syncthreads();   // sA staging (done by caller) now visible

#pragma unroll
    for (int ks = 0; ks < 4; ++ks) {
        short8 ah[2], al[2];
#pragma unroll
        for (int rf = 0; rf < 2; ++rf) {
            int off = (rf * 16 + lr) * 136 + ks * 32 + lk;
            ah[rf] = *(const short8*)&sAh[off];
            if (SPLIT_A) al[rf] = *(const short8*)&sAl[off];
        }
#pragma unroll
        for (int rf = 0; rf < 2; ++rf)
#pragma unroll
            for (int cf = 0; cf < 2; ++cf) {
                acc[rf][cf] = __builtin_amdgcn_mfma_f32_16x16x32_bf16(ah[rf], bh[cf][ks], acc[rf][cf], 0, 0, 0);
                acc[rf][cf] = __builtin_amdgcn_mfma_f32_16x16x32_bf16(ah[rf], bl[cf][ks], acc[rf][cf], 0, 0, 0);
                if (SPLIT_A)
                    acc[rf][cf] = __builtin_amdgcn_mfma_f32_16x16x32_bf16(al[rf], bh[cf][ks], acc[rf][cf], 0, 0, 0);
            }
    }

    // C/D layout: col = l&15, row = (l>>4)*4 + reg. Pack bf16 col-pairs via shfl_xor(1)
    // (lane^1 holds col^1); even lanes store one u32 word -> same layout k_agg consumes.
#pragma unroll
    for (int rf = 0; rf < 2; ++rf)
#pragma unroll
        for (int cf = 0; cf < 2; ++cf)
#pragma unroll
            for (int r = 0; r < 4; ++r) {
                unsigned b = f2bf_rne(acc[rf][cf][r]);
                unsigned p = (unsigned)__shfl_xor((int)b, 1);
                if (!(l & 1)) {
                    size_t row = r0 + rf * 16 + ((l >> 4) << 2) + r;
                    int c = n0 + cf * 16 + lr;           // even
                    Cb[(row * 128 + c) >> 1] = b | (p << 16);
                }
            }
}

// ---------------- fused: layer-1 MFMA GEMM (fp32 A, split) || edge histogram ----------------
// 9375 blocks = 3125 GEMM (b%3==0) + 6250 pass1. 17 KB LDS -> 8 blocks/CU (wave-capped),
// up from 5 with the old 32 KB fp32 staging; pass1 atomics get more concurrency.
__global__ __launch_bounds__(256) void k_gp(const float* __restrict__ A,
                                            const ushort* __restrict__ Wth,
                                            const ushort* __restrict__ Wtl,
                                            unsigned* __restrict__ Cb,
                                            const int* __restrict__ col,
                                            const float* __restrict__ ew,
                                            unsigned long long* packed,
                                            int* __restrict__ rank, int e) {
    __shared__ alignas(16) ushort sAh[32 * 136];
    __shared__ alignas(16) ushort sAl[32 * 136];
    int b = blockIdx.x;
    int sub = b % 3;
    int q = b / 3;
    int t = threadIdx.x;

    if (sub != 0) {
        int p = q * 2 + sub - 1;            // 0..6249
        int i = p * 256 + t;
        if (i < e) {
            int c = col[i];
            unsigned fe = (unsigned)__float2uint_rn(ew[i] * 1048576.0f);  // 20 frac bits
            unsigned long long inc = ((unsigned long long)fe << 24) | 1ull;
            unsigned long long old = atomicAdd(&packed[c], inc);
            rank[i] = (int)(old & 0xFFFFFFull);
        }
        return;
    }

    size_t r0 = (size_t)q * 32;
    const float4* A4 = (const float4*)(A + r0 * 128);
#pragma unroll
    for (int i = 0; i < 4; ++i) {
        int j = t + 256 * i;                // float4 idx 0..1023
        float4 f = A4[j];
        int rr = j >> 5;
        int cc = (j & 31) << 2;
        unsigned h0 = f2bf_rne(f.x), h1 = f2bf_rne(f.y), h2 = f2bf_rne(f.z), h3 = f2bf_rne(f.w);
        unsigned g0 = f2bf_rne(f.x - bf_lo(h0)), g1 = f2bf_rne(f.y - bf_lo(h1));
        unsigned g2 = f2bf_rne(f.z - bf_lo(h2)), g3 = f2bf_rne(f.w - bf_lo(h3));
        *(ushort4*)&sAh[rr * 136 + cc] = make_ushort4((ushort)h0, (ushort)h1, (ushort)h2, (ushort)h3);
        *(ushort4*)&sAl[rr * 136 + cc] = make_ushort4((ushort)g0, (ushort)g1, (ushort)g2, (ushort)g3);
    }
    // mfma_tile's __syncthreads covers sA visibility
    mfma_tile<true>(sAh, sAl, Wth, Wtl, Cb, r0, t);
}

// fused: exclusive scan of counts -> rowptr, plus dinv = rsqrt(deg)
__global__ __launch_bounds__(256) void k_scan1(const unsigned long long* __restrict__ packed,
                                               int* __restrict__ rowptr,
                                               int* __restrict__ part,
                                               float* __restrict__ dinv, int n) {
    __shared__ int s[256];
    int t = threadIdx.x;
    int i = blockIdx.x * 256 + t;
    unsigned long long pk = (i < n) ? packed[i] : 0ull;
    int v = (int)(pk & 0xFFFFFFull);
    if (i < n) {
        float deg = 1.0f + (float)(pk >> 24) * (1.0f / 1048576.0f);  // +1 self-loop
        dinv[i] = rsqrtf(deg);
    }
    s[t] = v;
    __syncthreads();
    for (int d = 1; d < 256; d <<= 1) {
        int y = (t >= d) ? s[t - d] : 0;
        __syncthreads();
        s[t] += y;
        __syncthreads();
    }
    if (i < n) rowptr[i] = s[t] - v;
    if (t == 255) part[blockIdx.x] = s[255];
}

__global__ __launch_bounds__(512) void k_scan2(int* part, int m) {
    __shared__ int s[512];
    int t = threadIdx.x;
    int v = (t < m) ? part[t] : 0;
    s[t] = v;
    __syncthreads();
    for (int d = 1; d < 512; d <<= 1) {
        int y = (t >= d) ? s[t - d] : 0;
        __syncthreads();
        s[t] += y;
        __syncthreads();
    }
    if (t < m) part[t] = s[t] - v;
}

__global__ __launch_bounds__(256) void k_scan3(int* rowptr, const int* __restrict__ part, int n, int e) {
    int i = blockIdx.x * 256 + threadIdx.x;
    if (i < n) rowptr[i] += part[blockIdx.x];
    if (i == 0) rowptr[n] = e;
}

// atomic-free CSR fill; (src, wn) packed -> one 8-byte scattered store per edge
__global__ __launch_bounds__(256) void k_fill(const int* __restrict__ row,
                                              const int* __restrict__ col,
                                              const float* __restrict__ ew,
                                              const int* __restrict__ rowptr,
                                              const int* __restrict__ rank,
                                              const float* __restrict__ dinv,
                                              uint2* __restrict__ meta, int e) {
    int i = blockIdx.x * 256 + threadIdx.x;
    if (i < e) {
        int c = col[i];
        int r = row[i];
        int p = rowptr[c] + rank[i];
        float w = dinv[r] * ew[i] * dinv[c];
        meta[p] = make_uint2((unsigned)r, __float_as_uint(w));
    }
}

// ---------------- MFMA GEMM with bf16 A (layers 2,3) -> bf16 out ----------------
__global__ __launch_bounds__(256) void k_gemm_b(const unsigned* __restrict__ Ab,
                                                const ushort* __restrict__ Wth,
                                                const ushort* __restrict__ Wtl,
                                                unsigned* __restrict__ Cb) {
    __shared__ alignas(16) ushort sA[32 * 136];
    int t = threadIdx.x;
    size_t r0 = (size_t)blockIdx.x * 32;

    const uint4* A4 = (const uint4*)(Ab + r0 * 64);   // 8 bf16 per uint4
#pragma unroll
    for (int i = 0; i < 2; ++i) {
        int j = t + 256 * i;          // uint4 idx 0..511
        uint4 u = A4[j];
        int rr = j >> 4;              // 16 uint4 per 128-col row
        int cc = (j & 15) << 3;
        *(uint4*)&sA[rr * 136 + cc] = u;   // 272B stride = 17*16B: aligned
    }
    mfma_tile<false>(sA, nullptr, Wth, Wtl, Cb, r0, t);
}

// ---------------- pull-aggregation over bf16 rows ----------------
// One wave per node; lane owns one bf16 pair. 8 gathers in flight per lane.
__global__ __launch_bounds__(256) void k_agg(const unsigned* __restrict__ XWb,
                                             const int* __restrict__ rowptr,
                                             const uint2* __restrict__ meta,
                                             const float* __restrict__ dinv,
                                             const float* __restrict__ bias,
                                             unsigned* __restrict__ outb,
                                             float* __restrict__ outf, int relu, int n) {
    int lane = threadIdx.x & 63;
    int node = blockIdx.x * 4 + (threadIdx.x >> 6);
    if (node >= n) return;

    float di = dinv[node];
    float selfw = di * di;
    unsigned uself = XWb[(size_t)node * 64 + lane];
    float2 bv = *(const float2*)(bias + lane * 2);
    float ax = fmaf(selfw, bf_lo(uself), bv.x);
    float ay = fmaf(selfw, bf_hi(uself), bv.y);

    int p0 = rowptr[node], p1 = rowptr[node + 1];
    for (int base = p0; base < p1; base += 64) {
        int m = p1 - base; if (m > 64) m = 64;
        int idx = base + (lane < m ? lane : m - 1);
        uint2 mv = meta[idx];
        int sv = (int)mv.x;
        float wv = __uint_as_float(mv.y);
        int j = 0;
        for (; j + 8 <= m; j += 8) {
            int s0 = __shfl(sv, j),     s1 = __shfl(sv, j + 1);
            int s2 = __shfl(sv, j + 2), s3 = __shfl(sv, j + 3);
            int s4 = __shfl(sv, j + 4), s5 = __shfl(sv, j + 5);
            int s6 = __shfl(sv, j + 6), s7 = __shfl(sv, j + 7);
            float w0 = __shfl(wv, j),     w1 = __shfl(wv, j + 1);
            float w2 = __shfl(wv, j + 2), w3 = __shfl(wv, j + 3);
            float w4 = __shfl(wv, j + 4), w5 = __shfl(wv, j + 5);
            float w6 = __shfl(wv, j + 6), w7 = __shfl(wv, j + 7);
            unsigned u0 = XWb[(size_t)s0 * 64 + lane];
            unsigned u1 = XWb[(size_t)s1 * 64 + lane];
            unsigned u2 = XWb[(size_t)s2 * 64 + lane];
            unsigned u3 = XWb[(size_t)s3 * 64 + lane];
            unsigned u4 = XWb[(size_t)s4 * 64 + lane];
            unsigned u5 = XWb[(size_t)s5 * 64 + lane];
            unsigned u6 = XWb[(size_t)s6 * 64 + lane];
            unsigned u7 = XWb[(size_t)s7 * 64 + lane];
            ax = fmaf(w0, bf_lo(u0), ax);  ay = fmaf(w0, bf_hi(u0), ay);
            ax = fmaf(w1, bf_lo(u1), ax);  ay = fmaf(w1, bf_hi(u1), ay);
            ax = fmaf(w2, bf_lo(u2), ax);  ay = fmaf(w2, bf_hi(u2), ay);
            ax = fmaf(w3, bf_lo(u3), ax);  ay = fmaf(w3, bf_hi(u3), ay);
            ax = fmaf(w4, bf_lo(u4), ax);  ay = fmaf(w4, bf_hi(u4), ay);
            ax = fmaf(w5, bf_lo(u5), ax);  ay = fmaf(w5, bf_hi(u5), ay);
            ax = fmaf(w6, bf_lo(u6), ax);  ay = fmaf(w6, bf_hi(u6), ay);
            ax = fmaf(w7, bf_lo(u7), ax);  ay = fmaf(w7, bf_hi(u7), ay);
        }
        for (; j + 4 <= m; j += 4) {
            int s0 = __shfl(sv, j),     s1 = __shfl(sv, j + 1);
            int s2 = __shfl(sv, j + 2), s3 = __shfl(sv, j + 3);
            float w0 = __shfl(wv, j),     w1 = __shfl(wv, j + 1);
            float w2 = __shfl(wv, j + 2), w3 = __shfl(wv, j + 3);
            unsigned u0 = XWb[(size_t)s0 * 64 + lane];
            unsigned u1 = XWb[(size_t)s1 * 64 + lane];
            unsigned u2 = XWb[(size_t)s2 * 64 + lane];
            unsigned u3 = XWb[(size_t)s3 * 64 + lane];
            ax = fmaf(w0, bf_lo(u0), ax);  ay = fmaf(w0, bf_hi(u0), ay);
            ax = fmaf(w1, bf_lo(u1), ax);  ay = fmaf(w1, bf_hi(u1), ay);
            ax = fmaf(w2, bf_lo(u2), ax);  ay = fmaf(w2, bf_hi(u2), ay);
            ax = fmaf(w3, bf_lo(u3), ax);  ay = fmaf(w3, bf_hi(u3), ay);
        }
        for (; j < m; ++j) {
            int s = __shfl(sv, j);
            float w = __shfl(wv, j);
            unsigned u = XWb[(size_t)s * 64 + lane];
            ax = fmaf(w, bf_lo(u), ax);
            ay = fmaf(w, bf_hi(u), ay);
        }
    }
    if (relu) {
        ax = fmaxf(ax, 0.0f);
        ay = fmaxf(ay, 0.0f);
        outb[(size_t)node * 64 + lane] = f2bf_rne(ax) | (f2bf_rne(ay) << 16);
    } else {
        *(float2*)(outf + (size_t)node * 128 + lane * 2) = make_float2(ax, ay);
    }
}

// ---------------- launcher ----------------
extern "C" void kernel_launch(void* const* d_in, const int* in_sizes, int n_in,
                              void* d_out, int out_size, void* d_ws, size_t ws_size,
                              hipStream_t stream) {
    const float* x  = (const float*)d_in[0];
    const int*   ei = (const int*)d_in[1];
    const float* ew = (const float*)d_in[2];
    const float* W1 = (const float*)d_in[3];
    const float* b1 = (const float*)d_in[4];
    const float* W2 = (const float*)d_in[5];
    const float* b2 = (const float*)d_in[6];
    const float* W3 = (const float*)d_in[7];
    const float* b3 = (const float*)d_in[8];
    float* out = (float*)d_out;

    const int n = NN, e = NE;
    const int* row = ei;
    const int* col = ei + e;

    char* ws = (char*)d_ws;
    size_t off = 0;
    auto alloc = [&](size_t bytes) -> void* {
        void* p = ws + off;
        off = (off + bytes + 255) & ~(size_t)255;
        return p;
    };
    unsigned*           hb     = (unsigned*)          alloc((size_t)n * 128 * 2);
    unsigned*           xwb    = (unsigned*)          alloc((size_t)n * 128 * 2);
    unsigned long long* packed = (unsigned long long*)alloc((size_t)n * 8);
    float*              dinv   = (float*)             alloc((size_t)n * 4);
    int*                rowptr = (int*)               alloc((size_t)(n + 1) * 4);
    int*                rank   = (int*)               alloc((size_t)e * 4);
    uint2*              meta   = (uint2*)             alloc((size_t)e * 8);
    int*                part   = (int*)               alloc(512 * 4);
    ushort*             wt     = (ushort*)            alloc(6 * 16384 * 2);  // 3x {W^T hi, W^T lo}
    (void)ws_size; (void)in_sizes; (void)n_in; (void)out_size;

    int nb = (n + 255) / 256;   // 391
    int eb = (e + 255) / 256;   // 6250
    int gb = n / 32;            // 3125
    int ab = (n + 3) / 4;       // 25000

    k_init<<<nb, 256, 0, stream>>>(packed, n);
    k_prep<<<64, 256, 0, stream>>>(W1, wt + 0 * 16384, wt + 1 * 16384);
    k_prep<<<64, 256, 0, stream>>>(W2, wt + 2 * 16384, wt + 3 * 16384);
    k_prep<<<64, 256, 0, stream>>>(W3, wt + 4 * 16384, wt + 5 * 16384);

    k_gp<<<gb + eb, 256, 0, stream>>>(x, wt + 0 * 16384, wt + 1 * 16384, xwb, col, ew, packed, rank, e);
    k_scan1<<<nb, 256, 0, stream>>>(packed, rowptr, part, dinv, n);
    k_scan2<<<1, 512, 0, stream>>>(part, nb);
    k_scan3<<<nb, 256, 0, stream>>>(rowptr, part, n, e);
    k_fill<<<eb, 256, 0, stream>>>(row, col, ew, rowptr, rank, dinv, meta, e);

    // Layer 1 aggregation -> bf16 hb
    k_agg<<<ab, 256, 0, stream>>>(xwb, rowptr, meta, dinv, b1, hb, (float*)nullptr, 1, n);
    // Layer 2
    k_gemm_b<<<gb, 256, 0, stream>>>(hb, wt + 2 * 16384, wt + 3 * 16384, xwb);
    k_agg<<<ab, 256, 0, stream>>>(xwb, rowptr, meta, dinv, b2, hb, (float*)nullptr, 1, n);
    // Layer 3 (fp32 out, no relu)
    k_gemm_b<<<gb, 256, 0, stream>>>(hb, wt + 4 * 16384, wt + 5 * 16384, xwb);
    k_agg<<<ab, 256, 0, stream>>>(xwb, rowptr, meta, dinv, b3, (unsigned*)nullptr, out, 0, n);
}